// Round 11
// baseline (251.866 us; speedup 1.0000x reference)
//
#include <hip/hip_runtime.h>

// Chamfer, B=4, N=M=8192 fp32 -> scalar. Round 14: r13 with FIXED workspace offsets.
// r13 post-mortem: absmax 5.6e5 was a BUG -- with NSLOT=16, sArr/tArr are 2MB each
// (65536*16*2B) but kernel_launch placed tArr at +1MB (overlapping sArr) and wpart at
// +2MB (overwriting tArr live). Kernels were fine. Corrected: sArr@0, tArr@2MB,
// wpart@4MB (6MB total). Everything else identical to r13:
//   K=16 2-limb payload (MFMA floor 6.9us, DS 5.1us), zero atomics (plain stores to
//   private wpart[dirb][csp][row], write-once; reduce fmin-folds 8 csp partials),
//   r9-proven 2-phase dbuf staging at __launch_bounds__(256,8).

#define BATCH 4
#define NPTS 8192
#define SETPTS (BATCH * NPTS)       // 32768
#define TOTPTS (2 * SETPTS)         // 65536
#define NSLOT 16                    // bf16 K-slots per point (all 16 used)
#define CHUNK_PTS 128               // col points staged per chunk = 4 tiles of 32
#define CSPLIT 8                    // col-splits per (dirb, rowblock)
#define COLS_PER (NPTS / CSPLIT)    // 1024 cols per block
#define CHUNKS_PER (COLS_PER / CHUNK_PTS)        // 8 chunks per block
#define CHUNK_BYTES (CHUNK_PTS * NSLOT * 2)      // 4096
#define RT 2                        // 32-row tiles per wave (64 rows/wave)
#define ROWS_BLK (4 * RT * 32)      // 256 rows per block
#define RBLK (NPTS / ROWS_BLK)      // 32 row-blocks

typedef __attribute__((ext_vector_type(8))) short bf16x8;
typedef __attribute__((ext_vector_type(16))) float f32x16;

__device__ __forceinline__ float bf16rn(float v) {  // round-to-nearest-even to bf16 value
  unsigned u = __float_as_uint(v);
  u = (u + 0x7FFFu + ((u >> 16) & 1u)) & 0xFFFF0000u;
  return __uint_as_float(u);
}
__device__ __forceinline__ unsigned short b2u(float v) {  // bf16 bits of a bf16-valued f32
  return (unsigned short)(__float_as_uint(v) >> 16);
}

// Per point (16 slots): s-vec (row role, carries -2) and t-vec (col role):
//   coord d (limbs a,b): s[4d+]: [-2a,-2a,-2b,-2b]   t[4d+]: [a,b,a,b]
//     -> all four limb products of -2 x_P x_Q
//   slots 12-13: s = split(|p|^2) = (g,h), t = (1,1)
//   slots 14-15: s = (1,1), t = split(|q|^2)
__global__ __launch_bounds__(256) void chamfer_prep_kernel(
    const float* __restrict__ p1, const float* __restrict__ p2,
    unsigned short* __restrict__ sArr, unsigned short* __restrict__ tArr,
    float* __restrict__ out) {
  const int i = blockIdx.x * 256 + threadIdx.x;  // 0..65535
  const float* src = (i < SETPTS) ? (p1 + 3 * (size_t)i) : (p2 + 3 * (size_t)(i - SETPTS));
  const float co[3] = {src[0], src[1], src[2]};
  union { unsigned short u[16]; uint4 v[2]; } sv, tv;
#pragma unroll
  for (int d = 0; d < 3; ++d) {
    const float v = co[d];
    const float a = bf16rn(v);
    const float bb = bf16rn(v - a);     // Sterbenz-exact residual, then rounded
    const unsigned short as = b2u(-2.f * a), bs = b2u(-2.f * bb);
    const unsigned short at = b2u(a), bt = b2u(bb);
    sv.u[4 * d + 0] = as; sv.u[4 * d + 1] = as;
    sv.u[4 * d + 2] = bs; sv.u[4 * d + 3] = bs;
    tv.u[4 * d + 0] = at; tv.u[4 * d + 1] = bt;
    tv.u[4 * d + 2] = at; tv.u[4 * d + 3] = bt;
  }
  const float sp = fmaf(co[0], co[0], fmaf(co[1], co[1], co[2] * co[2]));
  const float g = bf16rn(sp);
  const float h = bf16rn(sp - g);
  sv.u[12] = b2u(g); sv.u[13] = b2u(h);
  tv.u[12] = 0x3F80; tv.u[13] = 0x3F80;  // bf16(1.0)
  sv.u[14] = 0x3F80; sv.u[15] = 0x3F80;
  tv.u[14] = b2u(g); tv.u[15] = b2u(h);
  uint4* sd = (uint4*)(sArr + (size_t)i * NSLOT);
  uint4* td = (uint4*)(tArr + (size_t)i * NSLOT);
  sd[0] = sv.v[0]; sd[1] = sv.v[1];
  td[0] = tv.v[0]; td[1] = tv.v[1];
  if (i == 0) out[0] = 0.f;
}

// Block: 4 waves x 2 row-tiles(32) = 256 rows, 8 chunks (1024 cols) of its col-split.
// LDS chunk layout (pre-permuted global source, m173): 16B slot s within chunk holds
// (jt = s>>6, half = (s>>5)&1, col = s&31); reader's slot index for tile jt is exactly
// jt*64 + lane, so ds_read_b128 at lane*16 is linear/conflict-free AND is the
// 32x32x16 B-fragment (col = lane&31, k = (lane>>5)*8 + [0..7]).
__global__ __launch_bounds__(256, 8) void chamfer_mfma_kernel(
    const unsigned short* __restrict__ sArr, const unsigned short* __restrict__ tArr,
    float* __restrict__ wpart) {
  const int bx = blockIdx.x;
  const int dirb = bx & 7;         // bx%8 -> XCD-aligned: per-XCD L2 sees one dirb's t-set
  const int rblk = (bx >> 3) & (RBLK - 1);  // 0..31 (256 rows each)
  const int csp = bx >> 8;         // 0..7 (1024 cols each)
  const int dir = dirb >> 2, b = dirb & 3;
  const unsigned short* sb = sArr + (size_t)((dir ? SETPTS : 0) + b * NPTS) * NSLOT;
  const unsigned short* tb = tArr + (size_t)((dir ? 0 : SETPTS) + b * NPTS) * NSLOT;
  float* wp = wpart + ((size_t)dirb * CSPLIT + csp) * NPTS;  // private slice: no atomics

  const int t = threadIdx.x;
  const int lane = t & 63, wid = t >> 6;
  const int l31 = lane & 31, kh = lane >> 5;  // col/row in tile, k-group

  __shared__ uint4 sbuf[2][CHUNK_BYTES / 16];  // 2 x 4 KB
  char* cs = (char*)sbuf;

  const int rowbase = rblk * ROWS_BLK + wid * (RT * 32);  // wave owns 64 rows = 2 tiles
  bf16x8 a[RT];  // A-fragment: row = lane&31, k = (lane>>5)*8 + [0..7]
#pragma unroll
  for (int m = 0; m < RT; ++m)
    a[m] = *(const bf16x8*)(sb + (size_t)(rowbase + m * 32 + l31) * NSLOT + kh * 8);

  const char* gsrc;
  {
    const int jt = t >> 6, half = (t >> 5) & 1, col = t & 31;
    gsrc = (const char*)(tb + (size_t)(csp * COLS_PER + jt * 32 + col) * NSLOT + half * 8);
  }

  auto stage = [&](int chunk, int buf) {  // 1 global_load_lds (16B) per thread
    __builtin_amdgcn_global_load_lds(
        (const __attribute__((address_space(1))) void*)(gsrc + (size_t)chunk * CHUNK_BYTES),
        (__attribute__((address_space(3))) void*)(cs + buf * CHUNK_BYTES + t * 16), 16, 0, 0);
  };

  f32x16 acc[RT];
#pragma unroll
  for (int m = 0; m < RT; ++m)
#pragma unroll
    for (int r = 0; r < 16; ++r) acc[m][r] = INFINITY;
  const f32x16 zero = {0.f, 0.f, 0.f, 0.f, 0.f, 0.f, 0.f, 0.f,
                       0.f, 0.f, 0.f, 0.f, 0.f, 0.f, 0.f, 0.f};

  stage(0, 0);
  __syncthreads();

  int cur = 0;
  for (int c = 0; c < CHUNKS_PER; ++c) {
    if (c + 1 < CHUNKS_PER) stage(c + 1, cur ^ 1);  // prefetch next chunk
    const char* bbase = cs + cur * CHUNK_BYTES + lane * 16;
#pragma unroll
    for (int jt = 0; jt < 4; jt += 2) {  // 32-col tile PAIRS: min3 folds two results/op
      const bf16x8 bA = *(const bf16x8*)(bbase + jt * 1024);        // linear ds_read_b128
      const bf16x8 bB = *(const bf16x8*)(bbase + (jt + 1) * 1024);
#pragma unroll
      for (int m = 0; m < RT; ++m) {
        const f32x16 dA = __builtin_amdgcn_mfma_f32_32x32x16_bf16(a[m], bA, zero, 0, 0, 0);
        const f32x16 dB = __builtin_amdgcn_mfma_f32_32x32x16_bf16(a[m], bB, zero, 0, 0, 0);
#pragma unroll
        for (int r = 0; r < 16; ++r)
          acc[m][r] = fminf(fminf(acc[m][r], dA[r]), dB[r]);  // v_min3_f32
      }
    }
    __syncthreads();  // implicit vmcnt(0): next buffer staged; cur safe to overwrite
    cur ^= 1;
  }

  // fold the 32 col-lanes (xor masks 1..16 keep bit5 = kh) -> this block's row-mins
#pragma unroll
  for (int mk = 1; mk <= 16; mk <<= 1) {
#pragma unroll
    for (int m = 0; m < RT; ++m)
#pragma unroll
      for (int r = 0; r < 16; ++r)
        acc[m][r] = fminf(acc[m][r], __shfl_xor(acc[m][r], mk, 64));
  }
  if (l31 == 0) {  // C/D: col=lane&31, row=(reg&3)+8*(reg>>2)+4*(lane>>5) [m74/m101]
#pragma unroll
    for (int m = 0; m < RT; ++m)
#pragma unroll
      for (int r = 0; r < 16; ++r) {
        const int row = rowbase + m * 32 + (r & 3) + 8 * (r >> 2) + 4 * kh;
        wp[row] = acc[m][r];  // plain store to private slice -- no RMW, no sharing
      }
  }
}

__global__ __launch_bounds__(256) void chamfer_reduce_kernel(const float* __restrict__ wpart,
                                                             float* __restrict__ out) {
  // 65536 (dirb,row) outputs; fold 8 csp partials each. 64 blocks x 256 threads x 4.
  float s = 0.f;
  const int base = blockIdx.x * 1024 + threadIdx.x;
#pragma unroll
  for (int k = 0; k < 4; ++k) {
    const int o = base + k * 256;          // o = dirb*NPTS + row
    const int dirb = o >> 13, row = o & (NPTS - 1);
    float v = INFINITY;
#pragma unroll
    for (int csp = 0; csp < CSPLIT; ++csp)
      v = fminf(v, wpart[((size_t)dirb * CSPLIT + csp) * NPTS + row]);  // coalesced
    s += v;
  }
#pragma unroll
  for (int off = 32; off > 0; off >>= 1) s += __shfl_down(s, off, 64);
  __shared__ float wsum[4];
  const int lane = threadIdx.x & 63, wid = threadIdx.x >> 6;
  if (lane == 0) wsum[wid] = s;
  __syncthreads();
  if (threadIdx.x == 0) atomicAdd(out, wsum[0] + wsum[1] + wsum[2] + wsum[3]);
}

extern "C" void kernel_launch(void* const* d_in, const int* in_sizes, int n_in,
                              void* d_out, int out_size, void* d_ws, size_t ws_size,
                              hipStream_t stream) {
  const float* p1 = (const float*)d_in[0];
  const float* p2 = (const float*)d_in[1];
  float* out = (float*)d_out;
  // NSLOT=16 -> sArr/tArr are 65536*16*2B = 2MB EACH (r13 bug: tArr was at +1MB).
  unsigned short* sArr = (unsigned short*)d_ws;                       // [0, 2MB)
  unsigned short* tArr = (unsigned short*)((char*)d_ws + (2 << 20));  // [2MB, 4MB)
  float* wpart = (float*)((char*)d_ws + (4 << 20));                   // [4MB, 6MB)

  chamfer_prep_kernel<<<dim3(TOTPTS / 256), dim3(256), 0, stream>>>(p1, p2, sArr, tArr, out);
  chamfer_mfma_kernel<<<dim3(8 * RBLK * CSPLIT), dim3(256), 0, stream>>>(sArr, tArr, wpart);
  chamfer_reduce_kernel<<<dim3(64), dim3(256), 0, stream>>>(wpart, out);
}

// Round 12
// 84.685 us; speedup vs baseline: 2.9742x; 2.9742x over previous
//
#include <hip/hip_runtime.h>

// Chamfer, B=4, N=M=8192 fp32 -> scalar. Round 15: r14 with launch_bounds(256,4).
// r14 post-mortem: VGPR_Count=32 + WRITE 540MB/FETCH 344MB = REGISTER SPILL. The
// (256,8) bound caps 64 VGPR/wave but 32x32 acc state needs ~60+ (acc[2]=32 f32 +
// a[2]=8 + B + addr); compiler spilled acc to scratch inside the MFMA loop -> every
// accumulator round-trips HBM (190us, MfmaUtil 3.5%). r11/r12 ran this register
// footprint cleanly at (256,4)/(256,6). Single-variable fix: (256,4).
// Kept: K=16 2-limb payload (MFMA floor 6.9us, DS 5.1us), unchained 32x32x16,
// zero atomics (private wpart[dirb][csp][row] plain stores; reduce fmin-folds),
// 2-phase dbuf staging. absmax 0.0 expected (r14 passed the numeric check).

#define BATCH 4
#define NPTS 8192
#define SETPTS (BATCH * NPTS)       // 32768
#define TOTPTS (2 * SETPTS)         // 65536
#define NSLOT 16                    // bf16 K-slots per point (all 16 used)
#define CHUNK_PTS 128               // col points staged per chunk = 4 tiles of 32
#define CSPLIT 8                    // col-splits per (dirb, rowblock)
#define COLS_PER (NPTS / CSPLIT)    // 1024 cols per block
#define CHUNKS_PER (COLS_PER / CHUNK_PTS)        // 8 chunks per block
#define CHUNK_BYTES (CHUNK_PTS * NSLOT * 2)      // 4096
#define RT 2                        // 32-row tiles per wave (64 rows/wave)
#define ROWS_BLK (4 * RT * 32)      // 256 rows per block
#define RBLK (NPTS / ROWS_BLK)      // 32 row-blocks

typedef __attribute__((ext_vector_type(8))) short bf16x8;
typedef __attribute__((ext_vector_type(16))) float f32x16;

__device__ __forceinline__ float bf16rn(float v) {  // round-to-nearest-even to bf16 value
  unsigned u = __float_as_uint(v);
  u = (u + 0x7FFFu + ((u >> 16) & 1u)) & 0xFFFF0000u;
  return __uint_as_float(u);
}
__device__ __forceinline__ unsigned short b2u(float v) {  // bf16 bits of a bf16-valued f32
  return (unsigned short)(__float_as_uint(v) >> 16);
}

// Per point (16 slots): s-vec (row role, carries -2) and t-vec (col role):
//   coord d (limbs a,b): s[4d+]: [-2a,-2a,-2b,-2b]   t[4d+]: [a,b,a,b]
//     -> all four limb products of -2 x_P x_Q
//   slots 12-13: s = split(|p|^2) = (g,h), t = (1,1)
//   slots 14-15: s = (1,1), t = split(|q|^2)
__global__ __launch_bounds__(256) void chamfer_prep_kernel(
    const float* __restrict__ p1, const float* __restrict__ p2,
    unsigned short* __restrict__ sArr, unsigned short* __restrict__ tArr,
    float* __restrict__ out) {
  const int i = blockIdx.x * 256 + threadIdx.x;  // 0..65535
  const float* src = (i < SETPTS) ? (p1 + 3 * (size_t)i) : (p2 + 3 * (size_t)(i - SETPTS));
  const float co[3] = {src[0], src[1], src[2]};
  union { unsigned short u[16]; uint4 v[2]; } sv, tv;
#pragma unroll
  for (int d = 0; d < 3; ++d) {
    const float v = co[d];
    const float a = bf16rn(v);
    const float bb = bf16rn(v - a);     // Sterbenz-exact residual, then rounded
    const unsigned short as = b2u(-2.f * a), bs = b2u(-2.f * bb);
    const unsigned short at = b2u(a), bt = b2u(bb);
    sv.u[4 * d + 0] = as; sv.u[4 * d + 1] = as;
    sv.u[4 * d + 2] = bs; sv.u[4 * d + 3] = bs;
    tv.u[4 * d + 0] = at; tv.u[4 * d + 1] = bt;
    tv.u[4 * d + 2] = at; tv.u[4 * d + 3] = bt;
  }
  const float sp = fmaf(co[0], co[0], fmaf(co[1], co[1], co[2] * co[2]));
  const float g = bf16rn(sp);
  const float h = bf16rn(sp - g);
  sv.u[12] = b2u(g); sv.u[13] = b2u(h);
  tv.u[12] = 0x3F80; tv.u[13] = 0x3F80;  // bf16(1.0)
  sv.u[14] = 0x3F80; sv.u[15] = 0x3F80;
  tv.u[14] = b2u(g); tv.u[15] = b2u(h);
  uint4* sd = (uint4*)(sArr + (size_t)i * NSLOT);
  uint4* td = (uint4*)(tArr + (size_t)i * NSLOT);
  sd[0] = sv.v[0]; sd[1] = sv.v[1];
  td[0] = tv.v[0]; td[1] = tv.v[1];
  if (i == 0) out[0] = 0.f;
}

// Block: 4 waves x 2 row-tiles(32) = 256 rows, 8 chunks (1024 cols) of its col-split.
// LDS chunk layout (pre-permuted global source, m173): 16B slot s within chunk holds
// (jt = s>>6, half = (s>>5)&1, col = s&31); reader's slot index for tile jt is exactly
// jt*64 + lane, so ds_read_b128 at lane*16 is linear/conflict-free AND is the
// 32x32x16 B-fragment (col = lane&31, k = (lane>>5)*8 + [0..7]).
__global__ __launch_bounds__(256, 4) void chamfer_mfma_kernel(
    const unsigned short* __restrict__ sArr, const unsigned short* __restrict__ tArr,
    float* __restrict__ wpart) {
  const int bx = blockIdx.x;
  const int dirb = bx & 7;         // bx%8 -> XCD-aligned: per-XCD L2 sees one dirb's t-set
  const int rblk = (bx >> 3) & (RBLK - 1);  // 0..31 (256 rows each)
  const int csp = bx >> 8;         // 0..7 (1024 cols each)
  const int dir = dirb >> 2, b = dirb & 3;
  const unsigned short* sb = sArr + (size_t)((dir ? SETPTS : 0) + b * NPTS) * NSLOT;
  const unsigned short* tb = tArr + (size_t)((dir ? 0 : SETPTS) + b * NPTS) * NSLOT;
  float* wp = wpart + ((size_t)dirb * CSPLIT + csp) * NPTS;  // private slice: no atomics

  const int t = threadIdx.x;
  const int lane = t & 63, wid = t >> 6;
  const int l31 = lane & 31, kh = lane >> 5;  // col/row in tile, k-group

  __shared__ uint4 sbuf[2][CHUNK_BYTES / 16];  // 2 x 4 KB
  char* cs = (char*)sbuf;

  const int rowbase = rblk * ROWS_BLK + wid * (RT * 32);  // wave owns 64 rows = 2 tiles
  bf16x8 a[RT];  // A-fragment: row = lane&31, k = (lane>>5)*8 + [0..7]
#pragma unroll
  for (int m = 0; m < RT; ++m)
    a[m] = *(const bf16x8*)(sb + (size_t)(rowbase + m * 32 + l31) * NSLOT + kh * 8);

  const char* gsrc;
  {
    const int jt = t >> 6, half = (t >> 5) & 1, col = t & 31;
    gsrc = (const char*)(tb + (size_t)(csp * COLS_PER + jt * 32 + col) * NSLOT + half * 8);
  }

  auto stage = [&](int chunk, int buf) {  // 1 global_load_lds (16B) per thread
    __builtin_amdgcn_global_load_lds(
        (const __attribute__((address_space(1))) void*)(gsrc + (size_t)chunk * CHUNK_BYTES),
        (__attribute__((address_space(3))) void*)(cs + buf * CHUNK_BYTES + t * 16), 16, 0, 0);
  };

  f32x16 acc[RT];
#pragma unroll
  for (int m = 0; m < RT; ++m)
#pragma unroll
    for (int r = 0; r < 16; ++r) acc[m][r] = INFINITY;
  const f32x16 zero = {0.f, 0.f, 0.f, 0.f, 0.f, 0.f, 0.f, 0.f,
                       0.f, 0.f, 0.f, 0.f, 0.f, 0.f, 0.f, 0.f};

  stage(0, 0);
  __syncthreads();

  int cur = 0;
  for (int c = 0; c < CHUNKS_PER; ++c) {
    if (c + 1 < CHUNKS_PER) stage(c + 1, cur ^ 1);  // prefetch next chunk
    const char* bbase = cs + cur * CHUNK_BYTES + lane * 16;
#pragma unroll
    for (int jt = 0; jt < 4; jt += 2) {  // 32-col tile PAIRS: min3 folds two results/op
      const bf16x8 bA = *(const bf16x8*)(bbase + jt * 1024);        // linear ds_read_b128
      const bf16x8 bB = *(const bf16x8*)(bbase + (jt + 1) * 1024);
#pragma unroll
      for (int m = 0; m < RT; ++m) {
        const f32x16 dA = __builtin_amdgcn_mfma_f32_32x32x16_bf16(a[m], bA, zero, 0, 0, 0);
        const f32x16 dB = __builtin_amdgcn_mfma_f32_32x32x16_bf16(a[m], bB, zero, 0, 0, 0);
#pragma unroll
        for (int r = 0; r < 16; ++r)
          acc[m][r] = fminf(fminf(acc[m][r], dA[r]), dB[r]);  // v_min3_f32
      }
    }
    __syncthreads();  // implicit vmcnt(0): next buffer staged; cur safe to overwrite
    cur ^= 1;
  }

  // fold the 32 col-lanes (xor masks 1..16 keep bit5 = kh) -> this block's row-mins
#pragma unroll
  for (int mk = 1; mk <= 16; mk <<= 1) {
#pragma unroll
    for (int m = 0; m < RT; ++m)
#pragma unroll
      for (int r = 0; r < 16; ++r)
        acc[m][r] = fminf(acc[m][r], __shfl_xor(acc[m][r], mk, 64));
  }
  if (l31 == 0) {  // C/D: col=lane&31, row=(reg&3)+8*(reg>>2)+4*(lane>>5) [m74/m101]
#pragma unroll
    for (int m = 0; m < RT; ++m)
#pragma unroll
      for (int r = 0; r < 16; ++r) {
        const int row = rowbase + m * 32 + (r & 3) + 8 * (r >> 2) + 4 * kh;
        wp[row] = acc[m][r];  // plain store to private slice -- no RMW, no sharing
      }
  }
}

__global__ __launch_bounds__(256) void chamfer_reduce_kernel(const float* __restrict__ wpart,
                                                             float* __restrict__ out) {
  // 65536 (dirb,row) outputs; fold 8 csp partials each. 64 blocks x 256 threads x 4.
  float s = 0.f;
  const int base = blockIdx.x * 1024 + threadIdx.x;
#pragma unroll
  for (int k = 0; k < 4; ++k) {
    const int o = base + k * 256;          // o = dirb*NPTS + row
    const int dirb = o >> 13, row = o & (NPTS - 1);
    float v = INFINITY;
#pragma unroll
    for (int csp = 0; csp < CSPLIT; ++csp)
      v = fminf(v, wpart[((size_t)dirb * CSPLIT + csp) * NPTS + row]);  // coalesced
    s += v;
  }
#pragma unroll
  for (int off = 32; off > 0; off >>= 1) s += __shfl_down(s, off, 64);
  __shared__ float wsum[4];
  const int lane = threadIdx.x & 63, wid = threadIdx.x >> 6;
  if (lane == 0) wsum[wid] = s;
  __syncthreads();
  if (threadIdx.x == 0) atomicAdd(out, wsum[0] + wsum[1] + wsum[2] + wsum[3]);
}

extern "C" void kernel_launch(void* const* d_in, const int* in_sizes, int n_in,
                              void* d_out, int out_size, void* d_ws, size_t ws_size,
                              hipStream_t stream) {
  const float* p1 = (const float*)d_in[0];
  const float* p2 = (const float*)d_in[1];
  float* out = (float*)d_out;
  // NSLOT=16 -> sArr/tArr are 65536*16*2B = 2MB EACH.
  unsigned short* sArr = (unsigned short*)d_ws;                       // [0, 2MB)
  unsigned short* tArr = (unsigned short*)((char*)d_ws + (2 << 20));  // [2MB, 4MB)
  float* wpart = (float*)((char*)d_ws + (4 << 20));                   // [4MB, 6MB)

  chamfer_prep_kernel<<<dim3(TOTPTS / 256), dim3(256), 0, stream>>>(p1, p2, sArr, tArr, out);
  chamfer_mfma_kernel<<<dim3(8 * RBLK * CSPLIT), dim3(256), 0, stream>>>(sArr, tArr, wpart);
  chamfer_reduce_kernel<<<dim3(64), dim3(256), 0, stream>>>(wpart, out);
}

// Round 13
// 75.605 us; speedup vs baseline: 3.3313x; 1.1201x over previous
//
#include <hip/hip_runtime.h>

// Chamfer, B=4, N=M=8192 fp32 -> scalar. Round 16: swapped-operand MFMA + stage-once.
// r15 post-mortem: WIN (mfma ~27.8us, total 84.7). Remaining gap vs 17.5us model:
// the 160-shuffle/wave butterfly epilogue (DS pipe) + 16 barrier drains per block.
// Fix 1 (T12 idea): swap operands -- D[q][p] = mfma(A=t(Q), B=s(P)). Min-over-Q is
//   then over the 16 D-regs IN-LANE (7+1 min3 tree, same VALU count as before) and
//   the butterfly collapses to ONE shfl_xor(32)+fmin per m. acc: 32 VGPR -> 2.
// Fix 2: stage the whole 1024-col split (32KB) once -- 8 gload_lds/thread, one
//   __syncthreads, then 32 barrier-free tiles. LDS 32KB -> 4 blocks/CU at (256,4).
// Loads are byte-identical to r15 (same staging formula, same owned-frag load);
// only the MFMA argument order and the fold/store structure change.

#define BATCH 4
#define NPTS 8192
#define SETPTS (BATCH * NPTS)       // 32768
#define TOTPTS (2 * SETPTS)         // 65536
#define NSLOT 16                    // bf16 K-slots per point (all 16 used)
#define CSPLIT 8                    // col-splits per (dirb, rowblock)
#define COLS_PER (NPTS / CSPLIT)    // 1024 streamed Q points per block
#define NTILE (COLS_PER / 32)       // 32 Q-tiles per block
#define STAGE_BYTES (COLS_PER * NSLOT * 2)  // 32768
#define RT 2                        // 32-row P tiles per wave (64 P/wave)
#define ROWS_BLK (4 * RT * 32)      // 256 P rows per block
#define RBLK (NPTS / ROWS_BLK)      // 32 row-blocks

typedef __attribute__((ext_vector_type(8))) short bf16x8;
typedef __attribute__((ext_vector_type(16))) float f32x16;

__device__ __forceinline__ float bf16rn(float v) {  // round-to-nearest-even to bf16 value
  unsigned u = __float_as_uint(v);
  u = (u + 0x7FFFu + ((u >> 16) & 1u)) & 0xFFFF0000u;
  return __uint_as_float(u);
}
__device__ __forceinline__ unsigned short b2u(float v) {  // bf16 bits of a bf16-valued f32
  return (unsigned short)(__float_as_uint(v) >> 16);
}

// Per point (16 slots): s-vec (carries -2) and t-vec:
//   coord d (limbs a,b): s[4d+]: [-2a,-2a,-2b,-2b]   t[4d+]: [a,b,a,b]
//   slots 12-13: s = split(|p|^2) = (g,h), t = (1,1); slots 14-15: s = (1,1), t = split.
__global__ __launch_bounds__(256) void chamfer_prep_kernel(
    const float* __restrict__ p1, const float* __restrict__ p2,
    unsigned short* __restrict__ sArr, unsigned short* __restrict__ tArr,
    float* __restrict__ out) {
  const int i = blockIdx.x * 256 + threadIdx.x;  // 0..65535
  const float* src = (i < SETPTS) ? (p1 + 3 * (size_t)i) : (p2 + 3 * (size_t)(i - SETPTS));
  const float co[3] = {src[0], src[1], src[2]};
  union { unsigned short u[16]; uint4 v[2]; } sv, tv;
#pragma unroll
  for (int d = 0; d < 3; ++d) {
    const float v = co[d];
    const float a = bf16rn(v);
    const float bb = bf16rn(v - a);     // Sterbenz-exact residual, then rounded
    const unsigned short as = b2u(-2.f * a), bs = b2u(-2.f * bb);
    const unsigned short at = b2u(a), bt = b2u(bb);
    sv.u[4 * d + 0] = as; sv.u[4 * d + 1] = as;
    sv.u[4 * d + 2] = bs; sv.u[4 * d + 3] = bs;
    tv.u[4 * d + 0] = at; tv.u[4 * d + 1] = bt;
    tv.u[4 * d + 2] = at; tv.u[4 * d + 3] = bt;
  }
  const float sp = fmaf(co[0], co[0], fmaf(co[1], co[1], co[2] * co[2]));
  const float g = bf16rn(sp);
  const float h = bf16rn(sp - g);
  sv.u[12] = b2u(g); sv.u[13] = b2u(h);
  tv.u[12] = 0x3F80; tv.u[13] = 0x3F80;  // bf16(1.0)
  sv.u[14] = 0x3F80; sv.u[15] = 0x3F80;
  tv.u[14] = b2u(g); tv.u[15] = b2u(h);
  uint4* sd = (uint4*)(sArr + (size_t)i * NSLOT);
  uint4* td = (uint4*)(tArr + (size_t)i * NSLOT);
  sd[0] = sv.v[0]; sd[1] = sv.v[1];
  td[0] = tv.v[0]; td[1] = tv.v[1];
  if (i == 0) out[0] = 0.f;
}

// Block: 4 waves x 2 P-tiles(32) = 256 P rows; streams 1024 Q (32 tiles) staged ONCE.
// LDS layout (pre-permuted global source, m173): 16B slot s holds (jt=s>>6,
// half=(s>>5)&1, q=s&31); reader's ds_read_b128 at (jt*64+lane)*16 is linear,
// conflict-free, and is exactly the 32x32x16 A-fragment of the Q tile
// (row = lane&31 = q, k = (lane>>5)*8 + [0..7]).
__global__ __launch_bounds__(256, 4) void chamfer_mfma_kernel(
    const unsigned short* __restrict__ sArr, const unsigned short* __restrict__ tArr,
    float* __restrict__ wpart) {
  const int bx = blockIdx.x;
  const int dirb = bx & 7;         // bx%8 -> XCD-aligned
  const int rblk = (bx >> 3) & (RBLK - 1);  // 0..31 (256 P rows each)
  const int csp = bx >> 8;         // 0..7 (1024 Q cols each)
  const int dir = dirb >> 2, b = dirb & 3;
  const unsigned short* sb = sArr + (size_t)((dir ? SETPTS : 0) + b * NPTS) * NSLOT;
  const unsigned short* tb = tArr + (size_t)((dir ? 0 : SETPTS) + b * NPTS) * NSLOT;
  float* wp = wpart + ((size_t)dirb * CSPLIT + csp) * NPTS;  // private slice: no atomics

  const int t = threadIdx.x;
  const int lane = t & 63, wid = t >> 6;
  const int l31 = lane & 31, kh = lane >> 5;

  __shared__ uint4 sbuf[STAGE_BYTES / 16];  // 32 KB: the whole Q split, staged once
  char* cs = (char*)sbuf;

  const int rowbase = rblk * ROWS_BLK + wid * (RT * 32);  // wave owns 64 P = 2 tiles
  bf16x8 bP[RT];  // B-fragment: col = lane&31 = P point, k = (lane>>5)*8 + [0..7]
#pragma unroll
  for (int m = 0; m < RT; ++m)
    bP[m] = *(const bf16x8*)(sb + (size_t)(rowbase + m * 32 + l31) * NSLOT + kh * 8);

  // stage all 32 Q tiles: 8 x 16B per thread, pre-permuted source
#pragma unroll
  for (int k = 0; k < 8; ++k) {
    const int s = k * 256 + t;  // 0..2047
    const int jt = s >> 6, half = (s >> 5) & 1, q = s & 31;
    const char* g = (const char*)(tb + (size_t)(csp * COLS_PER + jt * 32 + q) * NSLOT + half * 8);
    __builtin_amdgcn_global_load_lds(
        (const __attribute__((address_space(1))) void*)g,
        (__attribute__((address_space(3))) void*)(cs + s * 16), 16, 0, 0);
  }
  __syncthreads();  // one barrier total; loop below is barrier-free

  float acc[RT];
#pragma unroll
  for (int m = 0; m < RT; ++m) acc[m] = INFINITY;
  const f32x16 zero = {0.f, 0.f, 0.f, 0.f, 0.f, 0.f, 0.f, 0.f,
                       0.f, 0.f, 0.f, 0.f, 0.f, 0.f, 0.f, 0.f};

#pragma unroll 4
  for (int jt = 0; jt < NTILE; ++jt) {
    const bf16x8 aQ = *(const bf16x8*)(cs + jt * 1024 + lane * 16);  // linear ds_read_b128
#pragma unroll
    for (int m = 0; m < RT; ++m) {
      // D[q][p]: col = lane&31 = p (lane-local!), row = q over the 16 regs + kh
      const f32x16 d = __builtin_amdgcn_mfma_f32_32x32x16_bf16(aQ, bP[m], zero, 0, 0, 0);
      // in-lane min over the 16 q-rows: 7 min3 + final min3 folding into acc
      float v = fminf(fminf(d[0], d[1]), d[2]);      // v_min3_f32
      v = fminf(fminf(v, d[3]), d[4]);
      v = fminf(fminf(v, d[5]), d[6]);
      v = fminf(fminf(v, d[7]), d[8]);
      v = fminf(fminf(v, d[9]), d[10]);
      v = fminf(fminf(v, d[11]), d[12]);
      v = fminf(fminf(v, d[13]), d[14]);
      acc[m] = fminf(fminf(acc[m], v), d[15]);
    }
  }

  // lanes l and l^32 hold complementary q-subsets for the SAME p: one swap+min
#pragma unroll
  for (int m = 0; m < RT; ++m) {
    const float v = fminf(acc[m], __shfl_xor(acc[m], 32, 64));
    if (kh == 0) wp[rowbase + m * 32 + l31] = v;  // plain store, no RMW
  }
}

__global__ __launch_bounds__(256) void chamfer_reduce_kernel(const float* __restrict__ wpart,
                                                             float* __restrict__ out) {
  // 65536 (dirb,row) outputs; fold 8 csp partials each. 64 blocks x 256 threads x 4.
  float s = 0.f;
  const int base = blockIdx.x * 1024 + threadIdx.x;
#pragma unroll
  for (int k = 0; k < 4; ++k) {
    const int o = base + k * 256;          // o = dirb*NPTS + row
    const int dirb = o >> 13, row = o & (NPTS - 1);
    float v = INFINITY;
#pragma unroll
    for (int csp = 0; csp < CSPLIT; ++csp)
      v = fminf(v, wpart[((size_t)dirb * CSPLIT + csp) * NPTS + row]);  // coalesced
    s += v;
  }
#pragma unroll
  for (int off = 32; off > 0; off >>= 1) s += __shfl_down(s, off, 64);
  __shared__ float wsum[4];
  const int lane = threadIdx.x & 63, wid = threadIdx.x >> 6;
  if (lane == 0) wsum[wid] = s;
  __syncthreads();
  if (threadIdx.x == 0) atomicAdd(out, wsum[0] + wsum[1] + wsum[2] + wsum[3]);
}

extern "C" void kernel_launch(void* const* d_in, const int* in_sizes, int n_in,
                              void* d_out, int out_size, void* d_ws, size_t ws_size,
                              hipStream_t stream) {
  const float* p1 = (const float*)d_in[0];
  const float* p2 = (const float*)d_in[1];
  float* out = (float*)d_out;
  // NSLOT=16 -> sArr/tArr are 65536*16*2B = 2MB EACH.
  unsigned short* sArr = (unsigned short*)d_ws;                       // [0, 2MB)
  unsigned short* tArr = (unsigned short*)((char*)d_ws + (2 << 20));  // [2MB, 4MB)
  float* wpart = (float*)((char*)d_ws + (4 << 20));                   // [4MB, 6MB)

  chamfer_prep_kernel<<<dim3(TOTPTS / 256), dim3(256), 0, stream>>>(p1, p2, sArr, tArr, out);
  chamfer_mfma_kernel<<<dim3(8 * RBLK * CSPLIT), dim3(256), 0, stream>>>(sArr, tArr, wpart);
  chamfer_reduce_kernel<<<dim3(64), dim3(256), 0, stream>>>(wpart, out);
}

// Round 14
// 73.749 us; speedup vs baseline: 3.4152x; 1.0252x over previous
//
#include <hip/hip_runtime.h>

// Chamfer, B=4, N=M=8192 fp32 -> scalar. Round 17: RT=4 + fused prep (2 kernels total).
// r16 post-mortem: WIN (mfma ~18.6us, total 75.6; prediction matched). Remaining model:
// MFMA 6.9 + DS 5.1 + min3 3.4 + ~3 residue. Two cuts:
//  1) RT=4: one ds_read_b128 feeds 4 MFMAs (DS 5.1 -> 2.6us). acc is 4 scalars; grid
//     1024 = exactly 4 blocks/CU at 32KB LDS, zero tail.
//  2) Fuse prep: block computes bP fragments from raw p1/p2 in regs and stages its
//     1024-Q split via compute + ds_write_b128 into the SAME slot layout the reader
//     used in r16 (slot jt*64+q and jt*64+32+q) -- read path byte-identical. Deletes
//     the prep kernel, one launch gap, and the 4MB sArr/tArr round-trip. Same limb
//     arithmetic -> same d2 bits -> absmax 0.0 expected.

#define BATCH 4
#define NPTS 8192
#define CSPLIT 8                    // col-splits per (dirb, rowblock)
#define COLS_PER (NPTS / CSPLIT)    // 1024 streamed Q points per block
#define NTILE (COLS_PER / 32)       // 32 Q-tiles per block
#define STAGE_BYTES (COLS_PER * 16 * 2)  // 32768 (16 bf16 slots/point)
#define RT 4                        // 32-row P tiles per wave (128 P/wave)
#define ROWS_BLK (4 * RT * 32)      // 512 P rows per block
#define RBLK (NPTS / ROWS_BLK)      // 16 row-blocks

typedef __attribute__((ext_vector_type(8))) short bf16x8;
typedef __attribute__((ext_vector_type(16))) float f32x16;

__device__ __forceinline__ float bf16rn(float v) {  // round-to-nearest-even to bf16 value
  unsigned u = __float_as_uint(v);
  u = (u + 0x7FFFu + ((u >> 16) & 1u)) & 0xFFFF0000u;
  return __uint_as_float(u);
}
__device__ __forceinline__ unsigned pk(float lo, float hi) {  // two bf16-valued f32 -> u32
  return (__float_as_uint(lo) >> 16) | (__float_as_uint(hi) & 0xFFFF0000u);
}

// 16-slot payload (identical arithmetic to r14-r16):
//   coord d (limbs a,b): s[4d+]: [-2a,-2a,-2b,-2b]   t[4d+]: [a,b,a,b]
//   slots 12-15: s = (g_p, h_p, 1, 1), t = (1, 1, g_q, h_q)  -> dot adds |p|^2+|q|^2.

// Block: 4 waves x 4 P-tiles(32) = 512 P rows; 1024 Q staged once (compute + ds_write).
// LDS slot s=(jt,half,q): point (jt,q) half0 at slot jt*64+q, half1 at jt*64+32+q.
// Reader ds_read_b128 at jt*1024 + lane*16 = slot jt*64+lane -> (q=lane&31, half=lane>>5)
// = exactly the 32x32x16 A-fragment of the Q tile (row=q, k=(lane>>5)*8+[0..7]).
__global__ __launch_bounds__(256, 4) void chamfer_mfma_kernel(
    const float* __restrict__ p1, const float* __restrict__ p2,
    float* __restrict__ wpart) {
  const int bx = blockIdx.x;
  const int dirb = bx & 7;                  // XCD-aligned direction/batch
  const int rblk = (bx >> 3) & (RBLK - 1);  // 0..15 (512 P rows each)
  const int csp = bx >> 7;                  // 0..7 (1024 Q cols each)
  const int dir = dirb >> 2, b = dirb & 3;
  const float* __restrict__ P = (dir ? p2 : p1) + (size_t)b * NPTS * 3;
  const float* __restrict__ Q = (dir ? p1 : p2) + (size_t)b * NPTS * 3;
  float* wp = wpart + ((size_t)dirb * CSPLIT + csp) * NPTS;  // private slice: no atomics

  const int t = threadIdx.x;
  const int lane = t & 63, wid = t >> 6;
  const int l31 = lane & 31, kh = lane >> 5;

  __shared__ uint4 sbuf[STAGE_BYTES / 16];  // 32 KB: the whole Q split
  char* cs = (char*)sbuf;

  // ---- stage Q: 4 points/thread, compute t-vec, ds_write both 16B halves ----
  {
    const int q = t & 31, jt0 = t >> 5;  // jt0 = 0..7
#pragma unroll
    for (int k = 0; k < 4; ++k) {
      const int jt = jt0 + 8 * k;
      const float* src = Q + 3 * (size_t)(csp * COLS_PER + jt * 32 + q);
      const float x = src[0], y = src[1], z = src[2];
      const float ax = bf16rn(x), bxl = bf16rn(x - ax);
      const float ay = bf16rn(y), byl = bf16rn(y - ay);
      const float az = bf16rn(z), bzl = bf16rn(z - az);
      const float sq = fmaf(x, x, fmaf(y, y, z * z));
      const float gq = bf16rn(sq), hq = bf16rn(sq - gq);
      uint4 h0, h1;
      h0.x = pk(ax, bxl); h0.y = h0.x;            // slots 0-3: (ax,bx,ax,bx)
      h0.z = pk(ay, byl); h0.w = h0.z;            // slots 4-7
      h1.x = pk(az, bzl); h1.y = h1.x;            // slots 8-11
      h1.z = 0x3F803F80u;                          // slots 12-13: (1,1)
      h1.w = pk(gq, hq);                           // slots 14-15: (gq,hq)
      sbuf[jt * 64 + q] = h0;
      sbuf[jt * 64 + 32 + q] = h1;
    }
  }

  // ---- bP fragments from raw P (each lane: its point's kh-half of the s-vec) ----
  const int rowbase = rblk * ROWS_BLK + wid * (RT * 32);  // wave owns 128 P = 4 tiles
  bf16x8 bP[RT];
#pragma unroll
  for (int m = 0; m < RT; ++m) {
    const float* src = P + 3 * (size_t)(rowbase + m * 32 + l31);
    const float x = src[0], y = src[1], z = src[2];
    const float ax = bf16rn(x), bxl = bf16rn(x - ax);
    const float ay = bf16rn(y), byl = bf16rn(y - ay);
    const float az = bf16rn(z), bzl = bf16rn(z - az);
    const float sp = fmaf(x, x, fmaf(y, y, z * z));
    const float gp = bf16rn(sp), hp = bf16rn(sp - gp);
    // s-vec: [0..7] = (-2ax x2, -2bx x2, -2ay x2, -2by x2); [8..15] = (-2az x2, -2bz x2, gp,hp,1,1)
    union { unsigned u[4]; bf16x8 v; } uu;
    uu.u[0] = kh ? pk(-2.f * az, -2.f * az) : pk(-2.f * ax, -2.f * ax);
    uu.u[1] = kh ? pk(-2.f * bzl, -2.f * bzl) : pk(-2.f * bxl, -2.f * bxl);
    uu.u[2] = kh ? pk(gp, hp) : pk(-2.f * ay, -2.f * ay);
    uu.u[3] = kh ? 0x3F803F80u : pk(-2.f * byl, -2.f * byl);
    bP[m] = uu.v;
  }

  __syncthreads();  // one barrier; loop below is barrier-free

  float acc[RT];
#pragma unroll
  for (int m = 0; m < RT; ++m) acc[m] = INFINITY;
  const f32x16 zero = {0.f, 0.f, 0.f, 0.f, 0.f, 0.f, 0.f, 0.f,
                       0.f, 0.f, 0.f, 0.f, 0.f, 0.f, 0.f, 0.f};

#pragma unroll 2
  for (int jt = 0; jt < NTILE; ++jt) {
    const bf16x8 aQ = *(const bf16x8*)(cs + jt * 1024 + lane * 16);  // linear ds_read_b128
#pragma unroll
    for (int m = 0; m < RT; ++m) {
      // D[q][p]: col = lane&31 = p (lane-local), rows = 16 q's in-reg (+kh half)
      const f32x16 d = __builtin_amdgcn_mfma_f32_32x32x16_bf16(aQ, bP[m], zero, 0, 0, 0);
      float v = fminf(fminf(d[0], d[1]), d[2]);      // v_min3_f32 tree, 8 ops/16 vals
      v = fminf(fminf(v, d[3]), d[4]);
      v = fminf(fminf(v, d[5]), d[6]);
      v = fminf(fminf(v, d[7]), d[8]);
      v = fminf(fminf(v, d[9]), d[10]);
      v = fminf(fminf(v, d[11]), d[12]);
      v = fminf(fminf(v, d[13]), d[14]);
      acc[m] = fminf(fminf(acc[m], v), d[15]);
    }
  }

  // lanes l and l^32 hold complementary q-subsets of the SAME p: one swap+min
#pragma unroll
  for (int m = 0; m < RT; ++m) {
    const float v = fminf(acc[m], __shfl_xor(acc[m], 32, 64));
    if (kh == 0) wp[rowbase + m * 32 + l31] = v;  // plain store, no RMW
  }
}

__global__ __launch_bounds__(256) void chamfer_reduce_kernel(const float* __restrict__ wpart,
                                                             float* __restrict__ out) {
  // 65536 (dirb,row) outputs; fold 8 csp partials each. 64 blocks x 256 threads x 4.
  float s = 0.f;
  const int base = blockIdx.x * 1024 + threadIdx.x;
#pragma unroll
  for (int k = 0; k < 4; ++k) {
    const int o = base + k * 256;          // o = dirb*NPTS + row
    const int dirb = o >> 13, row = o & (NPTS - 1);
    float v = INFINITY;
#pragma unroll
    for (int csp = 0; csp < CSPLIT; ++csp)
      v = fminf(v, wpart[((size_t)dirb * CSPLIT + csp) * NPTS + row]);  // coalesced
    s += v;
  }
#pragma unroll
  for (int off = 32; off > 0; off >>= 1) s += __shfl_down(s, off, 64);
  __shared__ float wsum[4];
  const int lane = threadIdx.x & 63, wid = threadIdx.x >> 6;
  if (lane == 0) wsum[wid] = s;
  __syncthreads();
  if (threadIdx.x == 0) atomicAdd(out, wsum[0] + wsum[1] + wsum[2] + wsum[3]);
}

extern "C" void kernel_launch(void* const* d_in, const int* in_sizes, int n_in,
                              void* d_out, int out_size, void* d_ws, size_t ws_size,
                              hipStream_t stream) {
  const float* p1 = (const float*)d_in[0];
  const float* p2 = (const float*)d_in[1];
  float* out = (float*)d_out;
  float* wpart = (float*)d_ws;  // 2 MB: 8 dirb x 8 csp x 8192 rows

  hipMemsetAsync(out, 0, sizeof(float), stream);
  chamfer_mfma_kernel<<<dim3(8 * RBLK * CSPLIT), dim3(256), 0, stream>>>(p1, p2, wpart);
  chamfer_reduce_kernel<<<dim3(64), dim3(256), 0, stream>>>(wpart, out);
}